// Round 4
// baseline (412.618 us; speedup 1.0000x reference)
//
#include <hip/hip_runtime.h>

#define Bn 4
#define Nn 4096000
#define Kn 409664
#define R1c 3686400u
#define NSEL 409600u

// ---- ws offsets (u32 units) ----
#define H1_OFF 0          // B*2048
#define H2_OFF 8192       // B*2048
#define H3_OFF 16384      // B*1024
#define CC_OFF 20480      // B (candidate counters)
#define ZERO_WORDS 20484
#define ST_OFF 20488      // B*8: 0=P,1=rem,2=mid,3=rem2,4=k_hi,5=SELKEY
#define BC_OFF 20520      // B*1000 (above counts -> scanned bc)
#define GE_OFF 24520      // B*1000
#define GT_OFF 28520      // B*1000
#define CNT_OFF 32520     // B

// ---- scratch inside `out` (u32 units) ----
#define SCC 1600000       // candidate keys per sample
#define GRP_BASE 6400000  // B*4000 wave-group bases
#define GCNT_BASE 6416000 // B*4000 wave-group counts

#define SCAP 768          // max buffered rows per scatter block

#define OUT_SP  ((size_t)Bn * Kn * 5)
#define OUT_VAL ((size_t)Bn * Kn * 9)

__device__ __forceinline__ unsigned fkey(float x) {
    unsigned u = __float_as_uint(x);
    return u ^ ((unsigned)((int)u >> 31) | 0x80000000u);
}

// ---------------- histogram pass 1: top 11 bits ----------------
// 4 lane-privatized copies (cp = lane&3), bins rotated by 8*cp for bank spread.
__device__ __forceinline__ void h1add(unsigned* h, unsigned cp, float v) {
    unsigned bin = fkey(v) >> 21;
    atomicAdd(&h[(cp << 11) + ((bin + (cp << 3)) & 2047u)], 1u);
}

__global__ void hist1_k(const float* __restrict__ cube, unsigned* __restrict__ ws) {
    __shared__ unsigned h[4 * 2048];
    int tid = threadIdx.x, blk = blockIdx.x;
    int b = blk / 250, c = blk % 250;
    unsigned cp = (unsigned)(tid & 3);
    for (int j = tid; j < 8192; j += 256) h[j] = 0;
    __syncthreads();
    const float4* p = (const float4*)(cube + (size_t)b * Nn + (size_t)c * 16384);
    for (int it = 0; it < 16; it += 4) {
        float4 v0 = p[(it + 0) * 256 + tid];
        float4 v1 = p[(it + 1) * 256 + tid];
        float4 v2 = p[(it + 2) * 256 + tid];
        float4 v3 = p[(it + 3) * 256 + tid];
        h1add(h, cp, v0.x); h1add(h, cp, v0.y); h1add(h, cp, v0.z); h1add(h, cp, v0.w);
        h1add(h, cp, v1.x); h1add(h, cp, v1.y); h1add(h, cp, v1.z); h1add(h, cp, v1.w);
        h1add(h, cp, v2.x); h1add(h, cp, v2.y); h1add(h, cp, v2.z); h1add(h, cp, v2.w);
        h1add(h, cp, v3.x); h1add(h, cp, v3.y); h1add(h, cp, v3.z); h1add(h, cp, v3.w);
    }
    __syncthreads();
    unsigned* g = ws + H1_OFF + b * 2048;
    for (int j = tid; j < 2048; j += 256) {
        unsigned s = 0;
#pragma unroll
        for (int k = 0; k < 4; ++k) s += h[(k << 11) + (((unsigned)j + (k << 3)) & 2047u)];
        if (s) atomicAdd(&g[j], s);
    }
}

// ---------------- pick bucket containing rank R1c ----------------
__global__ void pick1_k(unsigned* __restrict__ ws) {
    __shared__ unsigned sh[256];
    int tid = threadIdx.x, b = blockIdx.x;
    const unsigned* hist = ws + H1_OFF + b * 2048;
    unsigned loc[8], lsum = 0;
    for (int j = 0; j < 8; ++j) { loc[j] = hist[tid * 8 + j]; lsum += loc[j]; }
    sh[tid] = lsum; __syncthreads();
    for (int off = 1; off < 256; off <<= 1) {
        unsigned v = (tid >= off) ? sh[tid - off] : 0u; __syncthreads();
        sh[tid] += v; __syncthreads();
    }
    unsigned base = tid ? sh[tid - 1] : 0u;
    if (R1c >= base && R1c < base + lsum) {
        unsigned cacc = base;
        for (int j = 0; j < 8; ++j) {
            if (R1c < cacc + loc[j]) {
                ws[ST_OFF + b * 8 + 0] = (unsigned)(tid * 8 + j);
                ws[ST_OFF + b * 8 + 1] = R1c - cacc;
                break;
            }
            cacc += loc[j];
        }
    }
}

// ---------------- collect: barrier-light, wave-chunked ----------------
// Per 4096-block: above-count (top11 > P) -> BC; candidate keys (top11 == P)
// appended per wave into out-scratch with group base/count recorded.
__global__ void collect_k(const float* __restrict__ cube, unsigned* __restrict__ ou,
                          unsigned* __restrict__ ws) {
    __shared__ unsigned sh_ab[4];
    int tid = threadIdx.x, blk = blockIdx.x;
    int b = blk / 1000, c = blk % 1000;
    int lane = tid & 63, wid = tid >> 6;
    unsigned P = ws[ST_OFF + b * 8 + 0];
    const float4* pc = (const float4*)(cube + (size_t)b * Nn + (size_t)c * 4096 + (size_t)wid * 1024);
    float4 cv[4];
#pragma unroll
    for (int t = 0; t < 4; ++t) cv[t] = pc[t * 64 + lane];
    unsigned wab = 0, wcn = 0;
#pragma unroll
    for (int t = 0; t < 4; ++t) {
        float vv[4] = {cv[t].x, cv[t].y, cv[t].z, cv[t].w};
#pragma unroll
        for (int q = 0; q < 4; ++q) {
            unsigned top = fkey(vv[q]) >> 21;
            wab += (unsigned)__popcll(__ballot(top > P));
            wcn += (unsigned)__popcll(__ballot(top == P));
        }
    }
    unsigned base = 0;
    if (lane == 0) {
        sh_ab[wid] = wab;
        base = atomicAdd(&ws[CC_OFF + b], wcn);
        ou[GRP_BASE + b * 4000 + c * 4 + wid] = base;
        ou[GCNT_BASE + b * 4000 + c * 4 + wid] = wcn;
    }
    base = (unsigned)__shfl((int)base, 0, 64);
    __syncthreads();
    if (tid == 0) ws[BC_OFF + b * 1000 + c] = sh_ab[0] + sh_ab[1] + sh_ab[2] + sh_ab[3];

    unsigned long long lt = (1ull << lane) - 1ull;
    unsigned* dst = ou + (size_t)b * SCC;
    unsigned run = base;
#pragma unroll
    for (int t = 0; t < 4; ++t) {
        unsigned k0 = fkey(cv[t].x), k1 = fkey(cv[t].y), k2 = fkey(cv[t].z), k3 = fkey(cv[t].w);
        bool m0 = (k0 >> 21) == P, m1 = (k1 >> 21) == P, m2 = (k2 >> 21) == P, m3 = (k3 >> 21) == P;
        unsigned long long b0 = __ballot(m0), b1 = __ballot(m1), b2 = __ballot(m2), b3 = __ballot(m3);
        unsigned s_all = (unsigned)__popcll(b0 & lt) + (unsigned)__popcll(b1 & lt)
                       + (unsigned)__popcll(b2 & lt) + (unsigned)__popcll(b3 & lt);
        unsigned r = run + s_all;
        if (m0 && r < SCC) dst[r] = k0;
        r += (unsigned)m0;
        if (m1 && r < SCC) dst[r] = k1;
        r += (unsigned)m1;
        if (m2 && r < SCC) dst[r] = k2;
        r += (unsigned)m2;
        if (m3 && r < SCC) dst[r] = k3;
        run += (unsigned)__popcll(b0) + (unsigned)__popcll(b1)
             + (unsigned)__popcll(b2) + (unsigned)__popcll(b3);
    }
}

// ---------------- refine A: bits [20:10] over candidate keys ----------------
__global__ void hist2b_k(const unsigned* __restrict__ ou, unsigned* __restrict__ ws) {
    __shared__ unsigned h[2048];
    int tid = threadIdx.x, blk = blockIdx.x;
    int b = blk >> 6, g = blk & 63;
    unsigned M = min(ws[CC_OFF + b], (unsigned)SCC);
    for (int j = tid; j < 2048; j += 256) h[j] = 0;
    __syncthreads();
    const unsigned* src = ou + (size_t)b * SCC;
    for (unsigned i = (unsigned)g * 256u + tid; i < M; i += 64u * 256u)
        atomicAdd(&h[(src[i] >> 10) & 0x7FFu], 1u);
    __syncthreads();
    unsigned* gd = ws + H2_OFF + b * 2048;
    for (int j = tid; j < 2048; j += 256) if (h[j]) atomicAdd(&gd[j], h[j]);
}

__global__ void pick2b_k(unsigned* __restrict__ ws) {
    __shared__ unsigned sh[256];
    int tid = threadIdx.x, b = blockIdx.x;
    const unsigned* hist = ws + H2_OFF + b * 2048;
    unsigned r = ws[ST_OFF + b * 8 + 1];
    unsigned loc[8], lsum = 0;
    for (int j = 0; j < 8; ++j) { loc[j] = hist[tid * 8 + j]; lsum += loc[j]; }
    sh[tid] = lsum; __syncthreads();
    for (int off = 1; off < 256; off <<= 1) {
        unsigned v = (tid >= off) ? sh[tid - off] : 0u; __syncthreads();
        sh[tid] += v; __syncthreads();
    }
    unsigned base = tid ? sh[tid - 1] : 0u;
    if (r >= base && r < base + lsum) {
        unsigned cacc = base;
        for (int j = 0; j < 8; ++j) {
            if (r < cacc + loc[j]) {
                ws[ST_OFF + b * 8 + 2] = (unsigned)(tid * 8 + j);
                ws[ST_OFF + b * 8 + 3] = r - cacc;
                break;
            }
            cacc += loc[j];
        }
    }
}

// ---------------- refine B: low 10 bits ----------------
__global__ void hist3b_k(const unsigned* __restrict__ ou, unsigned* __restrict__ ws) {
    __shared__ unsigned h[1024];
    int tid = threadIdx.x, blk = blockIdx.x;
    int b = blk >> 6, g = blk & 63;
    unsigned mid = ws[ST_OFF + b * 8 + 2];
    unsigned M = min(ws[CC_OFF + b], (unsigned)SCC);
    for (int j = tid; j < 1024; j += 256) h[j] = 0;
    __syncthreads();
    const unsigned* src = ou + (size_t)b * SCC;
    for (unsigned i = (unsigned)g * 256u + tid; i < M; i += 64u * 256u) {
        unsigned k = src[i];
        if (((k >> 10) & 0x7FFu) == mid) atomicAdd(&h[k & 0x3FFu], 1u);
    }
    __syncthreads();
    unsigned* gd = ws + H3_OFF + b * 1024;
    for (int j = tid; j < 1024; j += 256) if (h[j]) atomicAdd(&gd[j], h[j]);
}

__global__ void pick3b_k(unsigned* __restrict__ ws) {
    __shared__ unsigned sh[256];
    int tid = threadIdx.x, b = blockIdx.x;
    const unsigned* hist = ws + H3_OFF + b * 1024;
    unsigned r = ws[ST_OFF + b * 8 + 3];
    unsigned loc[4], lsum = 0;
    for (int j = 0; j < 4; ++j) { loc[j] = hist[tid * 4 + j]; lsum += loc[j]; }
    sh[tid] = lsum; __syncthreads();
    for (int off = 1; off < 256; off <<= 1) {
        unsigned v = (tid >= off) ? sh[tid - off] : 0u; __syncthreads();
        sh[tid] += v; __syncthreads();
    }
    unsigned base = tid ? sh[tid - 1] : 0u;
    if (r >= base && r < base + lsum) {
        unsigned cacc = base;
        for (int j = 0; j < 4; ++j) {
            if (r < cacc + loc[j]) {
                unsigned P = ws[ST_OFF + b * 8 + 0];
                unsigned mid = ws[ST_OFF + b * 8 + 2];
                ws[ST_OFF + b * 8 + 4] = (P << 21) | (mid << 10) | (unsigned)(tid * 4 + j);
                break;
            }
            cacc += loc[j];
        }
    }
}

// ---------------- candidate counts (>=k_hi and >k_hi) per 4096-block ----------------
__global__ void cand_bc_k(const unsigned* __restrict__ ou, unsigned* __restrict__ ws) {
    __shared__ unsigned shg[4], sht[4];
    int tid = threadIdx.x, blk = blockIdx.x;
    int b = blk / 1000, c = blk % 1000;
    int lane = tid & 63, wid = tid >> 6;
    unsigned k_hi = ws[ST_OFF + b * 8 + 4];
    unsigned base = ou[GRP_BASE + b * 4000 + c * 4 + wid];
    unsigned n = ou[GCNT_BASE + b * 4000 + c * 4 + wid];
    const unsigned* keys = ou + (size_t)b * SCC;
    unsigned ge = 0, gt = 0;
    for (unsigned i = (unsigned)lane; i < n; i += 64u) {
        unsigned idx = base + i;
        unsigned key = (idx < SCC) ? keys[idx] : 0u;
        bool ok = idx < SCC;
        ge += (unsigned)__popcll(__ballot(ok && key >= k_hi));
        gt += (unsigned)__popcll(__ballot(ok && key > k_hi));
    }
    if (lane == 0) { shg[wid] = ge; sht[wid] = gt; }
    __syncthreads();
    if (tid == 0) {
        ws[GE_OFF + b * 1000 + c] = shg[0] + shg[1] + shg[2] + shg[3];
        ws[GT_OFF + b * 1000 + c] = sht[0] + sht[1] + sht[2] + sht[3];
    }
}

// ---------------- scan: decide SELKEY (tie case), exclusive scan of block counts ----------------
__global__ void scan_k(unsigned* __restrict__ ws) {
    __shared__ unsigned sh[256];
    int tid = threadIdx.x, b = blockIdx.x;
    unsigned* above = ws + BC_OFF + b * 1000;
    const unsigned* ge = ws + GE_OFF + b * 1000;
    const unsigned* gt = ws + GT_OFF + b * 1000;
    unsigned la[4], lg[4], lh[4];
    for (int j = 0; j < 4; ++j) {
        int idx = tid * 4 + j;
        bool in = idx < 1000;
        la[j] = in ? above[idx] : 0u;
        lg[j] = in ? ge[idx] : 0u;
        lh[j] = in ? gt[idx] : 0u;
    }
    // pass 1: total of above+ge
    unsigned s1 = la[0] + lg[0] + la[1] + lg[1] + la[2] + lg[2] + la[3] + lg[3];
    sh[tid] = s1; __syncthreads();
    for (int off = 1; off < 256; off <<= 1) {
        unsigned v = (tid >= off) ? sh[tid - off] : 0u; __syncthreads();
        sh[tid] += v; __syncthreads();
    }
    unsigned TG = sh[255];
    __syncthreads();
    bool sel = (TG == NSEL);   // vlo < vhi  => select x >= vhi ; else x > vhi
    unsigned lc[4];
    for (int j = 0; j < 4; ++j) lc[j] = la[j] + (sel ? lg[j] : lh[j]);
    unsigned s2 = lc[0] + lc[1] + lc[2] + lc[3];
    sh[tid] = s2; __syncthreads();
    for (int off = 1; off < 256; off <<= 1) {
        unsigned v = (tid >= off) ? sh[tid - off] : 0u; __syncthreads();
        sh[tid] += v; __syncthreads();
    }
    unsigned run = tid ? sh[tid - 1] : 0u;
    for (int j = 0; j < 4; ++j) {
        int idx = tid * 4 + j;
        if (idx < 1000) above[idx] = run;
        run += lc[j];
    }
    if (tid == 255) ws[CNT_OFF + b] = sh[255];
    if (tid == 0) {
        unsigned kh = ws[ST_OFF + b * 8 + 4];
        ws[ST_OFF + b * 8 + 5] = sel ? kh : kh + 1u;
    }
}

// ---------------- ordered scatter: LDS row buffer + coalesced region writes ----------------
__device__ __forceinline__ void stash_row(float* __restrict__ fbuf, unsigned* __restrict__ pbuf,
                                          unsigned r, int i, float x, float d) {
    int xi = i % 320;
    int t = i / 320;
    int yi = t % 320;
    int zi = t / 320;
    fbuf[r * 5 + 0] = (float)xi / 320.0f * 72.0f;
    fbuf[r * 5 + 1] = (float)yi / 320.0f * 32.0f;
    fbuf[r * 5 + 2] = (float)zi / 40.0f * 8.0f;
    fbuf[r * 5 + 3] = x / 1e13f;
    fbuf[r * 5 + 4] = d - 1.9326f;
    pbuf[r] = ((unsigned)zi << 18) | ((unsigned)yi << 9) | (unsigned)xi;
}

__device__ __forceinline__ void emit_row(float* __restrict__ out, int b, unsigned k,
                                         int i, float x, float d) {
    size_t row = (size_t)b * Kn + k;
    int xi = i % 320;
    int t = i / 320;
    int yi = t % 320;
    int zi = t / 320;
    float* f = out + row * 5;
    f[0] = (float)xi / 320.0f * 72.0f;
    f[1] = (float)yi / 320.0f * 32.0f;
    f[2] = (float)zi / 40.0f * 8.0f;
    f[3] = x / 1e13f;
    f[4] = d - 1.9326f;
    float* s = out + OUT_SP + row * 4;
    s[0] = (float)b; s[1] = (float)zi; s[2] = (float)yi; s[3] = (float)xi;
    out[OUT_VAL + row] = 1.0f;
}

__global__ void scatter_k(const float* __restrict__ cube, const float* __restrict__ dop,
                          float* __restrict__ out, const unsigned* __restrict__ ws) {
    __shared__ float fbuf[SCAP * 5];
    __shared__ unsigned pbuf[SCAP];
    __shared__ unsigned wcnt_sh[4];
    int tid = threadIdx.x, blk = blockIdx.x;
    int b = blk / 1000, c = blk % 1000;
    int lane = tid & 63, wid = tid >> 6;
    unsigned SELKEY = ws[ST_OFF + b * 8 + 5];

    size_t chunk = (size_t)b * Nn + (size_t)c * 4096 + (size_t)wid * 1024;
    const float4* pc = (const float4*)(cube + chunk);
    const float4* pd = (const float4*)(dop + chunk);

    float4 cv[4], dv4[4];
#pragma unroll
    for (int t = 0; t < 4; ++t) { cv[t] = pc[t * 64 + lane]; dv4[t] = pd[t * 64 + lane]; }
    unsigned wcnt = 0;
#pragma unroll
    for (int t = 0; t < 4; ++t) {
        wcnt += (unsigned)__popcll(__ballot(fkey(cv[t].x) >= SELKEY));
        wcnt += (unsigned)__popcll(__ballot(fkey(cv[t].y) >= SELKEY));
        wcnt += (unsigned)__popcll(__ballot(fkey(cv[t].z) >= SELKEY));
        wcnt += (unsigned)__popcll(__ballot(fkey(cv[t].w) >= SELKEY));
    }
    if (lane == 0) wcnt_sh[wid] = wcnt;
    __syncthreads();

    unsigned k0 = ws[BC_OFF + b * 1000 + c];
    unsigned total = wcnt_sh[0] + wcnt_sh[1] + wcnt_sh[2] + wcnt_sh[3];
    unsigned wbase = 0;
    for (int w = 0; w < wid; ++w) wbase += wcnt_sh[w];

    unsigned long long lt = (1ull << lane) - 1ull;
    int i0base = c * 4096 + wid * 1024 + lane * 4;

    if (total <= SCAP) {
        unsigned wb = wbase;
#pragma unroll
        for (int t = 0; t < 4; ++t) {
            bool m0 = fkey(cv[t].x) >= SELKEY, m1 = fkey(cv[t].y) >= SELKEY,
                 m2 = fkey(cv[t].z) >= SELKEY, m3 = fkey(cv[t].w) >= SELKEY;
            unsigned long long b0 = __ballot(m0), b1 = __ballot(m1), b2 = __ballot(m2), b3 = __ballot(m3);
            unsigned s_all = (unsigned)__popcll(b0 & lt) + (unsigned)__popcll(b1 & lt)
                           + (unsigned)__popcll(b2 & lt) + (unsigned)__popcll(b3 & lt);
            unsigned r = wb + s_all;
            int i0 = i0base + t * 256;
            if (m0) stash_row(fbuf, pbuf, r, i0 + 0, cv[t].x, dv4[t].x);
            r += (unsigned)m0;
            if (m1) stash_row(fbuf, pbuf, r, i0 + 1, cv[t].y, dv4[t].y);
            r += (unsigned)m1;
            if (m2) stash_row(fbuf, pbuf, r, i0 + 2, cv[t].z, dv4[t].z);
            r += (unsigned)m2;
            if (m3) stash_row(fbuf, pbuf, r, i0 + 3, cv[t].w, dv4[t].w);
            wb += (unsigned)__popcll(b0) + (unsigned)__popcll(b1)
                + (unsigned)__popcll(b2) + (unsigned)__popcll(b3);
        }
        __syncthreads();
        size_t row0 = (size_t)b * Kn + k0;
        float* f0 = out + row0 * 5;
        for (int j = tid; j < (int)(total * 5); j += 256) f0[j] = fbuf[j];
        float* s0 = out + OUT_SP + row0 * 4;
        float fb = (float)b;
        for (int j = tid; j < (int)(total * 4); j += 256) {
            unsigned pk = pbuf[j >> 2];
            int comp = j & 3;
            float val = (comp == 0) ? fb
                      : (comp == 1) ? (float)(pk >> 18)
                      : (comp == 2) ? (float)((pk >> 9) & 511u)
                                    : (float)(pk & 511u);
            s0[j] = val;
        }
        float* v0 = out + OUT_VAL + row0;
        for (int j = tid; j < (int)total; j += 256) v0[j] = 1.0f;
    } else {
        // fallback: direct scattered emit (never taken on bench data)
        unsigned wb = k0 + wbase;
#pragma unroll
        for (int t = 0; t < 4; ++t) {
            bool m0 = fkey(cv[t].x) >= SELKEY, m1 = fkey(cv[t].y) >= SELKEY,
                 m2 = fkey(cv[t].z) >= SELKEY, m3 = fkey(cv[t].w) >= SELKEY;
            unsigned long long b0 = __ballot(m0), b1 = __ballot(m1), b2 = __ballot(m2), b3 = __ballot(m3);
            unsigned s_all = (unsigned)__popcll(b0 & lt) + (unsigned)__popcll(b1 & lt)
                           + (unsigned)__popcll(b2 & lt) + (unsigned)__popcll(b3 & lt);
            unsigned r = wb + s_all;
            int i0 = i0base + t * 256;
            if (m0) emit_row(out, b, r, i0 + 0, cv[t].x, dv4[t].x);
            r += (unsigned)m0;
            if (m1) emit_row(out, b, r, i0 + 1, cv[t].y, dv4[t].y);
            r += (unsigned)m1;
            if (m2) emit_row(out, b, r, i0 + 2, cv[t].z, dv4[t].z);
            r += (unsigned)m2;
            if (m3) emit_row(out, b, r, i0 + 3, cv[t].w, dv4[t].w);
            wb += (unsigned)__popcll(b0) + (unsigned)__popcll(b1)
                + (unsigned)__popcll(b2) + (unsigned)__popcll(b3);
        }
    }
}

// ---------------- zero-fill invalid tail rows ----------------
__global__ void fill_k(float* __restrict__ out, const unsigned* __restrict__ ws) {
    int g = blockIdx.x * 256 + threadIdx.x;
    if (g >= Bn * Kn) return;
    int b = g / Kn;
    int k = g - b * Kn;
    if ((unsigned)k >= ws[CNT_OFF + b]) {
        size_t row = (size_t)g;
        float* f = out + row * 5;
        f[0] = 0.f; f[1] = 0.f; f[2] = 0.f; f[3] = 0.f; f[4] = 0.f;
        float* s = out + OUT_SP + row * 4;
        s[0] = 0.f; s[1] = 0.f; s[2] = 0.f; s[3] = 0.f;
        out[OUT_VAL + row] = 0.f;
    }
}

extern "C" void kernel_launch(void* const* d_in, const int* in_sizes, int n_in,
                              void* d_out, int out_size, void* d_ws, size_t ws_size,
                              hipStream_t stream) {
    const float* cube = (const float*)d_in[0];
    const float* dop = (const float*)d_in[1];
    float* out = (float*)d_out;
    unsigned* ws = (unsigned*)d_ws;
    unsigned* ou = (unsigned*)d_out;

    hipMemsetAsync(d_ws, 0, ZERO_WORDS * sizeof(unsigned), stream);

    hipLaunchKernelGGL(hist1_k, dim3(Bn * 250), dim3(256), 0, stream, cube, ws);
    hipLaunchKernelGGL(pick1_k, dim3(Bn), dim3(256), 0, stream, ws);
    hipLaunchKernelGGL(collect_k, dim3(Bn * 1000), dim3(256), 0, stream, cube, ou, ws);
    hipLaunchKernelGGL(hist2b_k, dim3(Bn * 64), dim3(256), 0, stream, ou, ws);
    hipLaunchKernelGGL(pick2b_k, dim3(Bn), dim3(256), 0, stream, ws);
    hipLaunchKernelGGL(hist3b_k, dim3(Bn * 64), dim3(256), 0, stream, ou, ws);
    hipLaunchKernelGGL(pick3b_k, dim3(Bn), dim3(256), 0, stream, ws);
    hipLaunchKernelGGL(cand_bc_k, dim3(Bn * 1000), dim3(256), 0, stream, ou, ws);
    hipLaunchKernelGGL(scan_k, dim3(Bn), dim3(256), 0, stream, ws);
    hipLaunchKernelGGL(scatter_k, dim3(Bn * 1000), dim3(256), 0, stream, cube, dop, out, ws);
    hipLaunchKernelGGL(fill_k, dim3((Bn * Kn + 255) / 256), dim3(256), 0, stream, out, ws);
}

// Round 7
// 241.600 us; speedup vs baseline: 1.7079x; 1.7079x over previous
//
#include <hip/hip_runtime.h>

#define Bn 4
#define Nn 4096000
#define Kn 409664
#define R1c 3686400u
#define NSEL 409600u

// ---- ws offsets (u32 units) ----
#define H1_OFF 0          // B*2048
#define H2_OFF 8192      // B*2048
#define H3_OFF 16384      // B*1024
#define ZERO_WORDS 20480
#define ST_OFF 20480      // B*8: 0=P,1=rem,2=mid,3=rem2,4=k_hi,5=SELKEY
#define BC_OFF 20512      // B*1000 (above counts -> scanned bc)
#define GE_OFF 24512      // B*1000
#define GT_OFF 28512      // B*1000
#define GC_OFF 32512      // B*1000 (candidate count per block)
#define CNT_OFF 36512     // B

// ---- deterministic candidate slots inside `out` (u32 units) ----
// slot(b,c) = b*1024000 + c*1024, capacity 1024 keys per 4096-elem block
#define CAPW 1024u

#define SCAP 768          // max buffered rows per scatter block

#define OUT_SP  ((size_t)Bn * Kn * 5)
#define OUT_VAL ((size_t)Bn * Kn * 9)

__device__ __forceinline__ unsigned fkey(float x) {
    unsigned u = __float_as_uint(x);
    return u ^ ((unsigned)((int)u >> 31) | 0x80000000u);
}

// ---------------- histogram pass 1: top 11 bits ----------------
// 4 lane-privatized copies (cp = lane&3), bins rotated by 8*cp for bank spread.
__device__ __forceinline__ void h1add(unsigned* h, unsigned cp, float v) {
    unsigned bin = fkey(v) >> 21;
    atomicAdd(&h[(cp << 11) + ((bin + (cp << 3)) & 2047u)], 1u);
}

__global__ void hist1_k(const float* __restrict__ cube, unsigned* __restrict__ ws) {
    __shared__ unsigned h[4 * 2048];
    int tid = threadIdx.x, blk = blockIdx.x;
    int b = blk / 250, c = blk % 250;
    unsigned cp = (unsigned)(tid & 3);
    for (int j = tid; j < 8192; j += 256) h[j] = 0;
    __syncthreads();
    const float4* p = (const float4*)(cube + (size_t)b * Nn + (size_t)c * 16384);
    for (int it = 0; it < 16; it += 4) {
        float4 v0 = p[(it + 0) * 256 + tid];
        float4 v1 = p[(it + 1) * 256 + tid];
        float4 v2 = p[(it + 2) * 256 + tid];
        float4 v3 = p[(it + 3) * 256 + tid];
        h1add(h, cp, v0.x); h1add(h, cp, v0.y); h1add(h, cp, v0.z); h1add(h, cp, v0.w);
        h1add(h, cp, v1.x); h1add(h, cp, v1.y); h1add(h, cp, v1.z); h1add(h, cp, v1.w);
        h1add(h, cp, v2.x); h1add(h, cp, v2.y); h1add(h, cp, v2.z); h1add(h, cp, v2.w);
        h1add(h, cp, v3.x); h1add(h, cp, v3.y); h1add(h, cp, v3.z); h1add(h, cp, v3.w);
    }
    __syncthreads();
    unsigned* g = ws + H1_OFF + b * 2048;
    for (int j = tid; j < 2048; j += 256) {
        unsigned s = 0;
#pragma unroll
        for (int k = 0; k < 4; ++k) s += h[(k << 11) + (((unsigned)j + (k << 3)) & 2047u)];
        if (s) atomicAdd(&g[j], s);
    }
}

// ---------------- pick bucket containing rank R1c ----------------
__global__ void pick1_k(unsigned* __restrict__ ws) {
    __shared__ unsigned sh[256];
    int tid = threadIdx.x, b = blockIdx.x;
    const unsigned* hist = ws + H1_OFF + b * 2048;
    unsigned loc[8], lsum = 0;
    for (int j = 0; j < 8; ++j) { loc[j] = hist[tid * 8 + j]; lsum += loc[j]; }
    sh[tid] = lsum; __syncthreads();
    for (int off = 1; off < 256; off <<= 1) {
        unsigned v = (tid >= off) ? sh[tid - off] : 0u; __syncthreads();
        sh[tid] += v; __syncthreads();
    }
    unsigned base = tid ? sh[tid - 1] : 0u;
    if (R1c >= base && R1c < base + lsum) {
        unsigned cacc = base;
        for (int j = 0; j < 8; ++j) {
            if (R1c < cacc + loc[j]) {
                ws[ST_OFF + b * 8 + 0] = (unsigned)(tid * 8 + j);
                ws[ST_OFF + b * 8 + 1] = R1c - cacc;
                break;
            }
            cacc += loc[j];
        }
    }
}

// ---------------- collect: deterministic slots, ZERO global atomics ----------------
// Per 4096-block c: above-count -> BC, candidate count -> GC,
// candidate keys compacted into out-slot [b*1024000 + c*1024, +1024).
// (Slot ordering is irrelevant: consumers are histograms/counts only.)
__global__ void collect_k(const float* __restrict__ cube, unsigned* __restrict__ ou,
                          unsigned* __restrict__ ws) {
    __shared__ unsigned sha[4], shc[4];
    int tid = threadIdx.x, blk = blockIdx.x;
    int b = blk / 1000, c = blk % 1000;
    int lane = tid & 63, wid = tid >> 6;
    unsigned P = ws[ST_OFF + b * 8 + 0];
    const float4* pc = (const float4*)(cube + (size_t)b * Nn + (size_t)c * 4096 + (size_t)wid * 1024);
    unsigned kk[16];
#pragma unroll
    for (int t = 0; t < 4; ++t) {
        float4 v = pc[t * 64 + lane];
        kk[4 * t + 0] = fkey(v.x); kk[4 * t + 1] = fkey(v.y);
        kk[4 * t + 2] = fkey(v.z); kk[4 * t + 3] = fkey(v.w);
    }
    unsigned wab = 0, wcn = 0;
#pragma unroll
    for (int j = 0; j < 16; ++j) {
        unsigned top = kk[j] >> 21;
        wab += (unsigned)__popcll(__ballot(top > P));
        wcn += (unsigned)__popcll(__ballot(top == P));
    }
    if (lane == 0) { sha[wid] = wab; shc[wid] = wcn; }
    __syncthreads();
    if (tid == 0) {
        ws[BC_OFF + b * 1000 + c] = sha[0] + sha[1] + sha[2] + sha[3];
        ws[GC_OFF + b * 1000 + c] = shc[0] + shc[1] + shc[2] + shc[3];
    }
    unsigned run = 0;
    for (int w = 0; w < wid; ++w) run += shc[w];
    unsigned long long lt = (1ull << lane) - 1ull;
    unsigned* dst = ou + (size_t)b * 1024000 + (size_t)c * 1024;
#pragma unroll
    for (int j = 0; j < 16; ++j) {
        bool m = (kk[j] >> 21) == P;
        unsigned long long bal = __ballot(m);
        unsigned r = run + (unsigned)__popcll(bal & lt);
        if (m && r < CAPW) dst[r] = kk[j];
        run += (unsigned)__popcll(bal);
    }
}

// ---------------- refine A: bits [20:10] over candidate slots ----------------
__global__ void hist2b_k(const unsigned* __restrict__ ou, unsigned* __restrict__ ws) {
    __shared__ unsigned h[2048];
    int tid = threadIdx.x, blk = blockIdx.x;
    int b = blk >> 6, g = blk & 63;
    for (int j = tid; j < 2048; j += 256) h[j] = 0;
    __syncthreads();
    for (int c = g; c < 1000; c += 64) {
        unsigned n = min(ws[GC_OFF + b * 1000 + c], CAPW);
        const unsigned* src = ou + (size_t)b * 1024000 + (size_t)c * 1024;
        for (unsigned i = tid; i < n; i += 256)
            atomicAdd(&h[(src[i] >> 10) & 0x7FFu], 1u);
    }
    __syncthreads();
    unsigned* gd = ws + H2_OFF + b * 2048;
    for (int j = tid; j < 2048; j += 256) if (h[j]) atomicAdd(&gd[j], h[j]);
}

__global__ void pick2b_k(unsigned* __restrict__ ws) {
    __shared__ unsigned sh[256];
    int tid = threadIdx.x, b = blockIdx.x;
    const unsigned* hist = ws + H2_OFF + b * 2048;
    unsigned r = ws[ST_OFF + b * 8 + 1];
    unsigned loc[8], lsum = 0;
    for (int j = 0; j < 8; ++j) { loc[j] = hist[tid * 8 + j]; lsum += loc[j]; }
    sh[tid] = lsum; __syncthreads();
    for (int off = 1; off < 256; off <<= 1) {
        unsigned v = (tid >= off) ? sh[tid - off] : 0u; __syncthreads();
        sh[tid] += v; __syncthreads();
    }
    unsigned base = tid ? sh[tid - 1] : 0u;
    if (r >= base && r < base + lsum) {
        unsigned cacc = base;
        for (int j = 0; j < 8; ++j) {
            if (r < cacc + loc[j]) {
                ws[ST_OFF + b * 8 + 2] = (unsigned)(tid * 8 + j);
                ws[ST_OFF + b * 8 + 3] = r - cacc;
                break;
            }
            cacc += loc[j];
        }
    }
}

// ---------------- refine B: low 10 bits ----------------
__global__ void hist3b_k(const unsigned* __restrict__ ou, unsigned* __restrict__ ws) {
    __shared__ unsigned h[1024];
    int tid = threadIdx.x, blk = blockIdx.x;
    int b = blk >> 6, g = blk & 63;
    unsigned mid = ws[ST_OFF + b * 8 + 2];
    for (int j = tid; j < 1024; j += 256) h[j] = 0;
    __syncthreads();
    for (int c = g; c < 1000; c += 64) {
        unsigned n = min(ws[GC_OFF + b * 1000 + c], CAPW);
        const unsigned* src = ou + (size_t)b * 1024000 + (size_t)c * 1024;
        for (unsigned i = tid; i < n; i += 256) {
            unsigned k = src[i];
            if (((k >> 10) & 0x7FFu) == mid) atomicAdd(&h[k & 0x3FFu], 1u);
        }
    }
    __syncthreads();
    unsigned* gd = ws + H3_OFF + b * 1024;
    for (int j = tid; j < 1024; j += 256) if (h[j]) atomicAdd(&gd[j], h[j]);
}

__global__ void pick3b_k(unsigned* __restrict__ ws) {
    __shared__ unsigned sh[256];
    int tid = threadIdx.x, b = blockIdx.x;
    const unsigned* hist = ws + H3_OFF + b * 1024;
    unsigned r = ws[ST_OFF + b * 8 + 3];
    unsigned loc[4], lsum = 0;
    for (int j = 0; j < 4; ++j) { loc[j] = hist[tid * 4 + j]; lsum += loc[j]; }
    sh[tid] = lsum; __syncthreads();
    for (int off = 1; off < 256; off <<= 1) {
        unsigned v = (tid >= off) ? sh[tid - off] : 0u; __syncthreads();
        sh[tid] += v; __syncthreads();
    }
    unsigned base = tid ? sh[tid - 1] : 0u;
    if (r >= base && r < base + lsum) {
        unsigned cacc = base;
        for (int j = 0; j < 4; ++j) {
            if (r < cacc + loc[j]) {
                unsigned P = ws[ST_OFF + b * 8 + 0];
                unsigned mid = ws[ST_OFF + b * 8 + 2];
                ws[ST_OFF + b * 8 + 4] = (P << 21) | (mid << 10) | (unsigned)(tid * 4 + j);
                break;
            }
            cacc += loc[j];
        }
    }
}

// ---------------- per-block candidate counts (>=k_hi and >k_hi) ----------------
__global__ void cand_bc_k(const unsigned* __restrict__ ou, unsigned* __restrict__ ws) {
    __shared__ unsigned sh[256];
    int tid = threadIdx.x, blk = blockIdx.x;
    int b = blk / 1000, c = blk % 1000;
    unsigned k_hi = ws[ST_OFF + b * 8 + 4];
    unsigned n = min(ws[GC_OFF + b * 1000 + c], CAPW);
    const unsigned* src = ou + (size_t)b * 1024000 + (size_t)c * 1024;
    unsigned ge = 0, gt = 0;
    for (unsigned i = tid; i < n; i += 256) {
        unsigned k = src[i];
        ge += (unsigned)(k >= k_hi);
        gt += (unsigned)(k > k_hi);
    }
    sh[tid] = (gt << 16) | ge;  // counts <= 1024, packed sum safe
    __syncthreads();
    for (int off = 128; off > 0; off >>= 1) {
        if (tid < off) sh[tid] += sh[tid + off];
        __syncthreads();
    }
    if (tid == 0) {
        ws[GE_OFF + b * 1000 + c] = sh[0] & 0xFFFFu;
        ws[GT_OFF + b * 1000 + c] = sh[0] >> 16;
    }
}

// ---------------- scan: decide SELKEY (tie case), exclusive scan of block counts ----------------
__global__ void scan_k(unsigned* __restrict__ ws) {
    __shared__ unsigned sh[256];
    int tid = threadIdx.x, b = blockIdx.x;
    unsigned* above = ws + BC_OFF + b * 1000;
    const unsigned* ge = ws + GE_OFF + b * 1000;
    const unsigned* gt = ws + GT_OFF + b * 1000;
    unsigned la[4], lg[4], lh[4];
    for (int j = 0; j < 4; ++j) {
        int idx = tid * 4 + j;
        bool in = idx < 1000;
        la[j] = in ? above[idx] : 0u;
        lg[j] = in ? ge[idx] : 0u;
        lh[j] = in ? gt[idx] : 0u;
    }
    unsigned s1 = la[0] + lg[0] + la[1] + lg[1] + la[2] + lg[2] + la[3] + lg[3];
    sh[tid] = s1; __syncthreads();
    for (int off = 1; off < 256; off <<= 1) {
        unsigned v = (tid >= off) ? sh[tid - off] : 0u; __syncthreads();
        sh[tid] += v; __syncthreads();
    }
    unsigned TG = sh[255];
    __syncthreads();
    bool sel = (TG == NSEL);   // vlo < vhi => select key >= k_hi ; tie => key > k_hi
    unsigned lc[4];
    for (int j = 0; j < 4; ++j) lc[j] = la[j] + (sel ? lg[j] : lh[j]);
    unsigned s2 = lc[0] + lc[1] + lc[2] + lc[3];
    sh[tid] = s2; __syncthreads();
    for (int off = 1; off < 256; off <<= 1) {
        unsigned v = (tid >= off) ? sh[tid - off] : 0u; __syncthreads();
        sh[tid] += v; __syncthreads();
    }
    unsigned run = tid ? sh[tid - 1] : 0u;
    for (int j = 0; j < 4; ++j) {
        int idx = tid * 4 + j;
        if (idx < 1000) above[idx] = run;
        run += lc[j];
    }
    if (tid == 255) ws[CNT_OFF + b] = sh[255];
    if (tid == 0) {
        unsigned kh = ws[ST_OFF + b * 8 + 4];
        ws[ST_OFF + b * 8 + 5] = sel ? kh : kh + 1u;
    }
}

// ---------------- ordered scatter: LDS row buffer + coalesced region writes ----------------
__device__ __forceinline__ void stash_row(float* __restrict__ fbuf, unsigned* __restrict__ pbuf,
                                          unsigned r, int i, float x, float d) {
    int xi = i % 320;
    int t = i / 320;
    int yi = t % 320;
    int zi = t / 320;
    fbuf[r * 5 + 0] = (float)xi / 320.0f * 72.0f;
    fbuf[r * 5 + 1] = (float)yi / 320.0f * 32.0f;
    fbuf[r * 5 + 2] = (float)zi / 40.0f * 8.0f;
    fbuf[r * 5 + 3] = x / 1e13f;
    fbuf[r * 5 + 4] = d - 1.9326f;
    pbuf[r] = ((unsigned)zi << 18) | ((unsigned)yi << 9) | (unsigned)xi;
}

__device__ __forceinline__ void emit_row(float* __restrict__ out, int b, unsigned k,
                                         int i, float x, float d) {
    size_t row = (size_t)b * Kn + k;
    int xi = i % 320;
    int t = i / 320;
    int yi = t % 320;
    int zi = t / 320;
    float* f = out + row * 5;
    f[0] = (float)xi / 320.0f * 72.0f;
    f[1] = (float)yi / 320.0f * 32.0f;
    f[2] = (float)zi / 40.0f * 8.0f;
    f[3] = x / 1e13f;
    f[4] = d - 1.9326f;
    float* s = out + OUT_SP + row * 4;
    s[0] = (float)b; s[1] = (float)zi; s[2] = (float)yi; s[3] = (float)xi;
    out[OUT_VAL + row] = 1.0f;
}

__global__ void scatter_k(const float* __restrict__ cube, const float* __restrict__ dop,
                          float* __restrict__ out, const unsigned* __restrict__ ws) {
    __shared__ float fbuf[SCAP * 5];
    __shared__ unsigned pbuf[SCAP];
    __shared__ unsigned wcnt_sh[4];
    int tid = threadIdx.x, blk = blockIdx.x;
    int b = blk / 1000, c = blk % 1000;
    int lane = tid & 63, wid = tid >> 6;
    unsigned SELKEY = ws[ST_OFF + b * 8 + 5];

    size_t chunk = (size_t)b * Nn + (size_t)c * 4096 + (size_t)wid * 1024;
    const float4* pc = (const float4*)(cube + chunk);
    const float4* pd = (const float4*)(dop + chunk);

    float vv[16], dd[16];
    unsigned kk[16];
#pragma unroll
    for (int t = 0; t < 4; ++t) {
        float4 a = pc[t * 64 + lane];
        float4 d = pd[t * 64 + lane];
        vv[4 * t + 0] = a.x; vv[4 * t + 1] = a.y; vv[4 * t + 2] = a.z; vv[4 * t + 3] = a.w;
        dd[4 * t + 0] = d.x; dd[4 * t + 1] = d.y; dd[4 * t + 2] = d.z; dd[4 * t + 3] = d.w;
        kk[4 * t + 0] = fkey(a.x); kk[4 * t + 1] = fkey(a.y);
        kk[4 * t + 2] = fkey(a.z); kk[4 * t + 3] = fkey(a.w);
    }
    unsigned wcnt = 0;
#pragma unroll
    for (int j = 0; j < 16; ++j)
        wcnt += (unsigned)__popcll(__ballot(kk[j] >= SELKEY));
    if (lane == 0) wcnt_sh[wid] = wcnt;
    __syncthreads();

    unsigned k0 = ws[BC_OFF + b * 1000 + c];
    unsigned total = wcnt_sh[0] + wcnt_sh[1] + wcnt_sh[2] + wcnt_sh[3];
    unsigned wbase = 0;
    for (int w = 0; w < wid; ++w) wbase += wcnt_sh[w];

    unsigned long long lt = (1ull << lane) - 1ull;
    int i0base = c * 4096 + wid * 1024 + lane * 4;

    // Phase 2: LANE-MAJOR ordering per t-group (element index order!):
    // rank(lane,q) = wb + sum_q' popc(b_q' & lt) + sum_{q'<q} m_q'(lane).
    if (total <= SCAP) {
        unsigned wb = wbase;
#pragma unroll
        for (int t = 0; t < 4; ++t) {
            bool m0 = kk[4 * t + 0] >= SELKEY, m1 = kk[4 * t + 1] >= SELKEY,
                 m2 = kk[4 * t + 2] >= SELKEY, m3 = kk[4 * t + 3] >= SELKEY;
            unsigned long long b0 = __ballot(m0), b1 = __ballot(m1), b2 = __ballot(m2), b3 = __ballot(m3);
            unsigned s_all = (unsigned)__popcll(b0 & lt) + (unsigned)__popcll(b1 & lt)
                           + (unsigned)__popcll(b2 & lt) + (unsigned)__popcll(b3 & lt);
            unsigned r = wb + s_all;
            int i0 = i0base + t * 256;
            if (m0) stash_row(fbuf, pbuf, r, i0 + 0, vv[4 * t + 0], dd[4 * t + 0]);
            r += (unsigned)m0;
            if (m1) stash_row(fbuf, pbuf, r, i0 + 1, vv[4 * t + 1], dd[4 * t + 1]);
            r += (unsigned)m1;
            if (m2) stash_row(fbuf, pbuf, r, i0 + 2, vv[4 * t + 2], dd[4 * t + 2]);
            r += (unsigned)m2;
            if (m3) stash_row(fbuf, pbuf, r, i0 + 3, vv[4 * t + 3], dd[4 * t + 3]);
            wb += (unsigned)__popcll(b0) + (unsigned)__popcll(b1)
                + (unsigned)__popcll(b2) + (unsigned)__popcll(b3);
        }
        __syncthreads();
        size_t row0 = (size_t)b * Kn + k0;
        float* f0 = out + row0 * 5;
        for (int j = tid; j < (int)(total * 5); j += 256) f0[j] = fbuf[j];
        float* s0 = out + OUT_SP + row0 * 4;
        float fb = (float)b;
        for (int j = tid; j < (int)(total * 4); j += 256) {
            unsigned pk = pbuf[j >> 2];
            int comp = j & 3;
            float val = (comp == 0) ? fb
                      : (comp == 1) ? (float)(pk >> 18)
                      : (comp == 2) ? (float)((pk >> 9) & 511u)
                                    : (float)(pk & 511u);
            s0[j] = val;
        }
        float* v0 = out + OUT_VAL + row0;
        for (int j = tid; j < (int)total; j += 256) v0[j] = 1.0f;
    } else {
        // fallback: direct scattered emit (never taken on bench data)
        unsigned wb = k0 + wbase;
#pragma unroll
        for (int t = 0; t < 4; ++t) {
            bool m0 = kk[4 * t + 0] >= SELKEY, m1 = kk[4 * t + 1] >= SELKEY,
                 m2 = kk[4 * t + 2] >= SELKEY, m3 = kk[4 * t + 3] >= SELKEY;
            unsigned long long b0 = __ballot(m0), b1 = __ballot(m1), b2 = __ballot(m2), b3 = __ballot(m3);
            unsigned s_all = (unsigned)__popcll(b0 & lt) + (unsigned)__popcll(b1 & lt)
                           + (unsigned)__popcll(b2 & lt) + (unsigned)__popcll(b3 & lt);
            unsigned r = wb + s_all;
            int i0 = i0base + t * 256;
            if (m0) emit_row(out, b, r, i0 + 0, vv[4 * t + 0], dd[4 * t + 0]);
            r += (unsigned)m0;
            if (m1) emit_row(out, b, r, i0 + 1, vv[4 * t + 1], dd[4 * t + 1]);
            r += (unsigned)m1;
            if (m2) emit_row(out, b, r, i0 + 2, vv[4 * t + 2], dd[4 * t + 2]);
            r += (unsigned)m2;
            if (m3) emit_row(out, b, r, i0 + 3, vv[4 * t + 3], dd[4 * t + 3]);
            wb += (unsigned)__popcll(b0) + (unsigned)__popcll(b1)
                + (unsigned)__popcll(b2) + (unsigned)__popcll(b3);
        }
    }
}

// ---------------- zero-fill invalid tail rows ----------------
__global__ void fill_k(float* __restrict__ out, const unsigned* __restrict__ ws) {
    int g = blockIdx.x * 256 + threadIdx.x;
    if (g >= Bn * Kn) return;
    int b = g / Kn;
    int k = g - b * Kn;
    if ((unsigned)k >= ws[CNT_OFF + b]) {
        size_t row = (size_t)g;
        float* f = out + row * 5;
        f[0] = 0.f; f[1] = 0.f; f[2] = 0.f; f[3] = 0.f; f[4] = 0.f;
        float* s = out + OUT_SP + row * 4;
        s[0] = 0.f; s[1] = 0.f; s[2] = 0.f; s[3] = 0.f;
        out[OUT_VAL + row] = 0.f;
    }
}

extern "C" void kernel_launch(void* const* d_in, const int* in_sizes, int n_in,
                              void* d_out, int out_size, void* d_ws, size_t ws_size,
                              hipStream_t stream) {
    const float* cube = (const float*)d_in[0];
    const float* dop = (const float*)d_in[1];
    float* out = (float*)d_out;
    unsigned* ws = (unsigned*)d_ws;
    unsigned* ou = (unsigned*)d_out;

    hipMemsetAsync(d_ws, 0, ZERO_WORDS * sizeof(unsigned), stream);

    hipLaunchKernelGGL(hist1_k, dim3(Bn * 250), dim3(256), 0, stream, cube, ws);
    hipLaunchKernelGGL(pick1_k, dim3(Bn), dim3(256), 0, stream, ws);
    hipLaunchKernelGGL(collect_k, dim3(Bn * 1000), dim3(256), 0, stream, cube, ou, ws);
    hipLaunchKernelGGL(hist2b_k, dim3(Bn * 64), dim3(256), 0, stream, ou, ws);
    hipLaunchKernelGGL(pick2b_k, dim3(Bn), dim3(256), 0, stream, ws);
    hipLaunchKernelGGL(hist3b_k, dim3(Bn * 64), dim3(256), 0, stream, ou, ws);
    hipLaunchKernelGGL(pick3b_k, dim3(Bn), dim3(256), 0, stream, ws);
    hipLaunchKernelGGL(cand_bc_k, dim3(Bn * 1000), dim3(256), 0, stream, ou, ws);
    hipLaunchKernelGGL(scan_k, dim3(Bn), dim3(256), 0, stream, ws);
    hipLaunchKernelGGL(scatter_k, dim3(Bn * 1000), dim3(256), 0, stream, cube, dop, out, ws);
    hipLaunchKernelGGL(fill_k, dim3((Bn * Kn + 255) / 256), dim3(256), 0, stream, out, ws);
}

// Round 8
// 240.223 us; speedup vs baseline: 1.7177x; 1.0057x over previous
//
#include <hip/hip_runtime.h>

#define Bn 4
#define Nn 4096000
#define Kn 409664
#define R1c 3686400u
#define NSEL 409600u

// ---- ws offsets (u32 units) ----
#define H1_OFF 0          // B*2048
#define H2_OFF 8192       // B*2048
#define H3_OFF 16384      // B*1024
#define ZERO_WORDS 20480
#define ST_OFF 20480      // B*8: 0=P,1=rem,2=mid,3=rem2,4=k_hi,5=SELKEY
#define BC_OFF 20512      // B*1000 (above counts -> scanned bc)
#define GE_OFF 24512      // B*1000
#define GT_OFF 28512      // B*1000
#define GC_OFF 32512      // B*1000 (candidate count per block)
#define CNT_OFF 36512     // B

// ---- deterministic candidate slots inside `out` (u32 units) ----
// slot(b,c) = b*1024000 + c*1024, capacity 1024 keys per 4096-elem block
#define CAPW 1024u

#define SCAP 768          // max buffered rows per scatter block

#define OUT_SP  ((size_t)Bn * Kn * 5)
#define OUT_VAL ((size_t)Bn * Kn * 9)

__device__ __forceinline__ unsigned fkey(float x) {
    unsigned u = __float_as_uint(x);
    return u ^ ((unsigned)((int)u >> 31) | 0x80000000u);
}

// ---------------- histogram pass 1: top 11 bits ----------------
// 4 lane-privatized copies (cp = lane&3), bins rotated by 8*cp for bank spread.
__device__ __forceinline__ void h1add(unsigned* h, unsigned cp, float v) {
    unsigned bin = fkey(v) >> 21;
    atomicAdd(&h[(cp << 11) + ((bin + (cp << 3)) & 2047u)], 1u);
}

__global__ void hist1_k(const float* __restrict__ cube, unsigned* __restrict__ ws) {
    __shared__ unsigned h[4 * 2048];
    int tid = threadIdx.x, blk = blockIdx.x;
    int b = blk / 250, c = blk % 250;
    unsigned cp = (unsigned)(tid & 3);
    for (int j = tid; j < 8192; j += 256) h[j] = 0;
    __syncthreads();
    const float4* p = (const float4*)(cube + (size_t)b * Nn + (size_t)c * 16384);
    for (int it = 0; it < 16; it += 4) {
        float4 v0 = p[(it + 0) * 256 + tid];
        float4 v1 = p[(it + 1) * 256 + tid];
        float4 v2 = p[(it + 2) * 256 + tid];
        float4 v3 = p[(it + 3) * 256 + tid];
        h1add(h, cp, v0.x); h1add(h, cp, v0.y); h1add(h, cp, v0.z); h1add(h, cp, v0.w);
        h1add(h, cp, v1.x); h1add(h, cp, v1.y); h1add(h, cp, v1.z); h1add(h, cp, v1.w);
        h1add(h, cp, v2.x); h1add(h, cp, v2.y); h1add(h, cp, v2.z); h1add(h, cp, v2.w);
        h1add(h, cp, v3.x); h1add(h, cp, v3.y); h1add(h, cp, v3.z); h1add(h, cp, v3.w);
    }
    __syncthreads();
    unsigned* g = ws + H1_OFF + b * 2048;
    for (int j = tid; j < 2048; j += 256) {
        unsigned s = 0;
#pragma unroll
        for (int k = 0; k < 4; ++k) s += h[(k << 11) + (((unsigned)j + (k << 3)) & 2047u)];
        if (s) atomicAdd(&g[j], s);
    }
}

// ---------------- pick bucket containing rank R1c ----------------
__global__ void pick1_k(unsigned* __restrict__ ws) {
    __shared__ unsigned sh[256];
    int tid = threadIdx.x, b = blockIdx.x;
    const unsigned* hist = ws + H1_OFF + b * 2048;
    unsigned loc[8], lsum = 0;
    for (int j = 0; j < 8; ++j) { loc[j] = hist[tid * 8 + j]; lsum += loc[j]; }
    sh[tid] = lsum; __syncthreads();
    for (int off = 1; off < 256; off <<= 1) {
        unsigned v = (tid >= off) ? sh[tid - off] : 0u; __syncthreads();
        sh[tid] += v; __syncthreads();
    }
    unsigned base = tid ? sh[tid - 1] : 0u;
    if (R1c >= base && R1c < base + lsum) {
        unsigned cacc = base;
        for (int j = 0; j < 8; ++j) {
            if (R1c < cacc + loc[j]) {
                ws[ST_OFF + b * 8 + 0] = (unsigned)(tid * 8 + j);
                ws[ST_OFF + b * 8 + 1] = R1c - cacc;
                break;
            }
            cacc += loc[j];
        }
    }
}

// ---------------- collect: deterministic slots, zero global atomics ----------------
// Candidate ballots computed ONCE and reused for count + compaction.
__global__ void collect_k(const float* __restrict__ cube, unsigned* __restrict__ ou,
                          unsigned* __restrict__ ws) {
    __shared__ unsigned sha[4], shc[4];
    int tid = threadIdx.x, blk = blockIdx.x;
    int b = blk / 1000, c = blk % 1000;
    int lane = tid & 63, wid = tid >> 6;
    unsigned P = ws[ST_OFF + b * 8 + 0];
    const float4* pc = (const float4*)(cube + (size_t)b * Nn + (size_t)c * 4096 + (size_t)wid * 1024);
    unsigned kk[16];
#pragma unroll
    for (int t = 0; t < 4; ++t) {
        float4 v = pc[t * 64 + lane];
        kk[4 * t + 0] = fkey(v.x); kk[4 * t + 1] = fkey(v.y);
        kk[4 * t + 2] = fkey(v.z); kk[4 * t + 3] = fkey(v.w);
    }
    unsigned long long bc[16];
    unsigned wab = 0, wcn = 0;
#pragma unroll
    for (int j = 0; j < 16; ++j) {
        unsigned top = kk[j] >> 21;
        wab += (unsigned)__popcll(__ballot(top > P));
        bc[j] = __ballot(top == P);
        wcn += (unsigned)__popcll(bc[j]);
    }
    if (lane == 0) { sha[wid] = wab; shc[wid] = wcn; }
    __syncthreads();
    if (tid == 0) {
        ws[BC_OFF + b * 1000 + c] = sha[0] + sha[1] + sha[2] + sha[3];
        ws[GC_OFF + b * 1000 + c] = shc[0] + shc[1] + shc[2] + shc[3];
    }
    unsigned run = 0;
    for (int w = 0; w < wid; ++w) run += shc[w];
    unsigned long long lt = (1ull << lane) - 1ull;
    unsigned* dst = ou + (size_t)b * 1024000 + (size_t)c * 1024;
#pragma unroll
    for (int j = 0; j < 16; ++j) {
        bool m = (kk[j] >> 21) == P;
        unsigned r = run + (unsigned)__popcll(bc[j] & lt);
        if (m && r < CAPW) dst[r] = kk[j];
        run += (unsigned)__popcll(bc[j]);
    }
}

// ---------------- refine A: bits [20:10] over candidate slots ----------------
__global__ void hist2b_k(const unsigned* __restrict__ ou, unsigned* __restrict__ ws) {
    __shared__ unsigned h[2048];
    int tid = threadIdx.x, blk = blockIdx.x;
    int b = blk >> 6, g = blk & 63;
    for (int j = tid; j < 2048; j += 256) h[j] = 0;
    __syncthreads();
    for (int c = g; c < 1000; c += 64) {
        unsigned n = min(ws[GC_OFF + b * 1000 + c], CAPW);
        const unsigned* src = ou + (size_t)b * 1024000 + (size_t)c * 1024;
        for (unsigned i = tid; i < n; i += 256)
            atomicAdd(&h[(src[i] >> 10) & 0x7FFu], 1u);
    }
    __syncthreads();
    unsigned* gd = ws + H2_OFF + b * 2048;
    for (int j = tid; j < 2048; j += 256) if (h[j]) atomicAdd(&gd[j], h[j]);
}

__global__ void pick2b_k(unsigned* __restrict__ ws) {
    __shared__ unsigned sh[256];
    int tid = threadIdx.x, b = blockIdx.x;
    const unsigned* hist = ws + H2_OFF + b * 2048;
    unsigned r = ws[ST_OFF + b * 8 + 1];
    unsigned loc[8], lsum = 0;
    for (int j = 0; j < 8; ++j) { loc[j] = hist[tid * 8 + j]; lsum += loc[j]; }
    sh[tid] = lsum; __syncthreads();
    for (int off = 1; off < 256; off <<= 1) {
        unsigned v = (tid >= off) ? sh[tid - off] : 0u; __syncthreads();
        sh[tid] += v; __syncthreads();
    }
    unsigned base = tid ? sh[tid - 1] : 0u;
    if (r >= base && r < base + lsum) {
        unsigned cacc = base;
        for (int j = 0; j < 8; ++j) {
            if (r < cacc + loc[j]) {
                ws[ST_OFF + b * 8 + 2] = (unsigned)(tid * 8 + j);
                ws[ST_OFF + b * 8 + 3] = r - cacc;
                break;
            }
            cacc += loc[j];
        }
    }
}

// ---------------- refine B: low 10 bits ----------------
__global__ void hist3b_k(const unsigned* __restrict__ ou, unsigned* __restrict__ ws) {
    __shared__ unsigned h[1024];
    int tid = threadIdx.x, blk = blockIdx.x;
    int b = blk >> 6, g = blk & 63;
    unsigned mid = ws[ST_OFF + b * 8 + 2];
    for (int j = tid; j < 1024; j += 256) h[j] = 0;
    __syncthreads();
    for (int c = g; c < 1000; c += 64) {
        unsigned n = min(ws[GC_OFF + b * 1000 + c], CAPW);
        const unsigned* src = ou + (size_t)b * 1024000 + (size_t)c * 1024;
        for (unsigned i = tid; i < n; i += 256) {
            unsigned k = src[i];
            if (((k >> 10) & 0x7FFu) == mid) atomicAdd(&h[k & 0x3FFu], 1u);
        }
    }
    __syncthreads();
    unsigned* gd = ws + H3_OFF + b * 1024;
    for (int j = tid; j < 1024; j += 256) if (h[j]) atomicAdd(&gd[j], h[j]);
}

__global__ void pick3b_k(unsigned* __restrict__ ws) {
    __shared__ unsigned sh[256];
    int tid = threadIdx.x, b = blockIdx.x;
    const unsigned* hist = ws + H3_OFF + b * 1024;
    unsigned r = ws[ST_OFF + b * 8 + 3];
    unsigned loc[4], lsum = 0;
    for (int j = 0; j < 4; ++j) { loc[j] = hist[tid * 4 + j]; lsum += loc[j]; }
    sh[tid] = lsum; __syncthreads();
    for (int off = 1; off < 256; off <<= 1) {
        unsigned v = (tid >= off) ? sh[tid - off] : 0u; __syncthreads();
        sh[tid] += v; __syncthreads();
    }
    unsigned base = tid ? sh[tid - 1] : 0u;
    if (r >= base && r < base + lsum) {
        unsigned cacc = base;
        for (int j = 0; j < 4; ++j) {
            if (r < cacc + loc[j]) {
                unsigned P = ws[ST_OFF + b * 8 + 0];
                unsigned mid = ws[ST_OFF + b * 8 + 2];
                ws[ST_OFF + b * 8 + 4] = (P << 21) | (mid << 10) | (unsigned)(tid * 4 + j);
                break;
            }
            cacc += loc[j];
        }
    }
}

// ---------------- per-block candidate counts (>=k_hi and >k_hi) ----------------
__global__ void cand_bc_k(const unsigned* __restrict__ ou, unsigned* __restrict__ ws) {
    __shared__ unsigned sh[256];
    int tid = threadIdx.x, blk = blockIdx.x;
    int b = blk / 1000, c = blk % 1000;
    unsigned k_hi = ws[ST_OFF + b * 8 + 4];
    unsigned n = min(ws[GC_OFF + b * 1000 + c], CAPW);
    const unsigned* src = ou + (size_t)b * 1024000 + (size_t)c * 1024;
    unsigned ge = 0, gt = 0;
    for (unsigned i = tid; i < n; i += 256) {
        unsigned k = src[i];
        ge += (unsigned)(k >= k_hi);
        gt += (unsigned)(k > k_hi);
    }
    sh[tid] = (gt << 16) | ge;  // counts <= 1024, packed sum safe
    __syncthreads();
    for (int off = 128; off > 0; off >>= 1) {
        if (tid < off) sh[tid] += sh[tid + off];
        __syncthreads();
    }
    if (tid == 0) {
        ws[GE_OFF + b * 1000 + c] = sh[0] & 0xFFFFu;
        ws[GT_OFF + b * 1000 + c] = sh[0] >> 16;
    }
}

// ---------------- scan: decide SELKEY (tie case), exclusive scan of block counts ----------------
__global__ void scan_k(unsigned* __restrict__ ws) {
    __shared__ unsigned sh[256];
    int tid = threadIdx.x, b = blockIdx.x;
    unsigned* above = ws + BC_OFF + b * 1000;
    const unsigned* ge = ws + GE_OFF + b * 1000;
    const unsigned* gt = ws + GT_OFF + b * 1000;
    unsigned la[4], lg[4], lh[4];
    for (int j = 0; j < 4; ++j) {
        int idx = tid * 4 + j;
        bool in = idx < 1000;
        la[j] = in ? above[idx] : 0u;
        lg[j] = in ? ge[idx] : 0u;
        lh[j] = in ? gt[idx] : 0u;
    }
    unsigned s1 = la[0] + lg[0] + la[1] + lg[1] + la[2] + lg[2] + la[3] + lg[3];
    sh[tid] = s1; __syncthreads();
    for (int off = 1; off < 256; off <<= 1) {
        unsigned v = (tid >= off) ? sh[tid - off] : 0u; __syncthreads();
        sh[tid] += v; __syncthreads();
    }
    unsigned TG = sh[255];
    __syncthreads();
    bool sel = (TG == NSEL);   // vlo < vhi => select key >= k_hi ; tie => key > k_hi
    unsigned lc[4];
    for (int j = 0; j < 4; ++j) lc[j] = la[j] + (sel ? lg[j] : lh[j]);
    unsigned s2 = lc[0] + lc[1] + lc[2] + lc[3];
    sh[tid] = s2; __syncthreads();
    for (int off = 1; off < 256; off <<= 1) {
        unsigned v = (tid >= off) ? sh[tid - off] : 0u; __syncthreads();
        sh[tid] += v; __syncthreads();
    }
    unsigned run = tid ? sh[tid - 1] : 0u;
    for (int j = 0; j < 4; ++j) {
        int idx = tid * 4 + j;
        if (idx < 1000) above[idx] = run;
        run += lc[j];
    }
    if (tid == 255) ws[CNT_OFF + b] = sh[255];
    if (tid == 0) {
        unsigned kh = ws[ST_OFF + b * 8 + 4];
        ws[ST_OFF + b * 8 + 5] = sel ? kh : kh + 1u;
    }
}

// ---------------- ordered scatter: index-stash + dense row phase ----------------
__device__ __forceinline__ void emit_row(float* __restrict__ out, int b, unsigned k,
                                         int i, float x, float d) {
    size_t row = (size_t)b * Kn + k;
    int xi = i % 320;
    int t = i / 320;
    int yi = t % 320;
    int zi = t / 320;
    float* f = out + row * 5;
    f[0] = (float)xi / 320.0f * 72.0f;
    f[1] = (float)yi / 320.0f * 32.0f;
    f[2] = (float)zi / 40.0f * 8.0f;
    f[3] = x / 1e13f;
    f[4] = d - 1.9326f;
    float* s = out + OUT_SP + row * 4;
    s[0] = (float)b; s[1] = (float)zi; s[2] = (float)yi; s[3] = (float)xi;
    out[OUT_VAL + row] = 1.0f;
}

__global__ void scatter_k(const float* __restrict__ cube, const float* __restrict__ dop,
                          float* __restrict__ out, const unsigned* __restrict__ ws) {
    __shared__ float fbuf[SCAP * 5];
    __shared__ unsigned si[SCAP];
    __shared__ unsigned wcnt_sh[4];
    int tid = threadIdx.x, blk = blockIdx.x;
    int b = blk / 1000, c = blk % 1000;
    int lane = tid & 63, wid = tid >> 6;
    unsigned SELKEY = ws[ST_OFF + b * 8 + 5];

    size_t chunk = (size_t)b * Nn + (size_t)c * 4096 + (size_t)wid * 1024;
    const float4* pc = (const float4*)(cube + chunk);

    unsigned kk[16];
#pragma unroll
    for (int t = 0; t < 4; ++t) {
        float4 a = pc[t * 64 + lane];
        kk[4 * t + 0] = fkey(a.x); kk[4 * t + 1] = fkey(a.y);
        kk[4 * t + 2] = fkey(a.z); kk[4 * t + 3] = fkey(a.w);
    }
    // ballots once, reused for count AND ranks
    unsigned long long bb[16];
    unsigned wcnt = 0;
#pragma unroll
    for (int j = 0; j < 16; ++j) {
        bb[j] = __ballot(kk[j] >= SELKEY);
        wcnt += (unsigned)__popcll(bb[j]);
    }
    if (lane == 0) wcnt_sh[wid] = wcnt;
    __syncthreads();

    unsigned k0 = ws[BC_OFF + b * 1000 + c];
    unsigned total = wcnt_sh[0] + wcnt_sh[1] + wcnt_sh[2] + wcnt_sh[3];
    unsigned wbase = 0;
    for (int w = 0; w < wid; ++w) wbase += wcnt_sh[w];

    unsigned long long lt = (1ull << lane) - 1ull;
    int i0base = c * 4096 + wid * 1024 + lane * 4;

    if (total <= SCAP) {
        // divergent stash: element index only (lane-major order per t-group)
        unsigned wb = wbase;
#pragma unroll
        for (int t = 0; t < 4; ++t) {
            bool m0 = kk[4 * t + 0] >= SELKEY, m1 = kk[4 * t + 1] >= SELKEY,
                 m2 = kk[4 * t + 2] >= SELKEY, m3 = kk[4 * t + 3] >= SELKEY;
            unsigned s_all = (unsigned)__popcll(bb[4 * t + 0] & lt) + (unsigned)__popcll(bb[4 * t + 1] & lt)
                           + (unsigned)__popcll(bb[4 * t + 2] & lt) + (unsigned)__popcll(bb[4 * t + 3] & lt);
            unsigned r = wb + s_all;
            int i0 = i0base + t * 256;
            if (m0) si[r] = (unsigned)(i0 + 0);
            r += (unsigned)m0;
            if (m1) si[r] = (unsigned)(i0 + 1);
            r += (unsigned)m1;
            if (m2) si[r] = (unsigned)(i0 + 2);
            r += (unsigned)m2;
            if (m3) si[r] = (unsigned)(i0 + 3);
            wb += (unsigned)__popcll(bb[4 * t + 0]) + (unsigned)__popcll(bb[4 * t + 1])
                + (unsigned)__popcll(bb[4 * t + 2]) + (unsigned)__popcll(bb[4 * t + 3]);
        }
        __syncthreads();

        // dense per-row phase: all lanes active; sp-row written directly as float4
        const float* cb = cube + (size_t)b * Nn;
        const float* db = dop + (size_t)b * Nn;
        size_t row0 = (size_t)b * Kn + k0;
        float fb = (float)b;
        for (unsigned r = tid; r < total; r += 256) {
            unsigned i = si[r];
            float x = cb[i];
            float d = db[i];
            unsigned xi = i % 320u;
            unsigned tt = i / 320u;
            unsigned yi = tt % 320u;
            unsigned zi = tt / 320u;
            fbuf[r * 5 + 0] = (float)xi / 320.0f * 72.0f;
            fbuf[r * 5 + 1] = (float)yi / 320.0f * 32.0f;
            fbuf[r * 5 + 2] = (float)zi / 40.0f * 8.0f;
            fbuf[r * 5 + 3] = x / 1e13f;
            fbuf[r * 5 + 4] = d - 1.9326f;
            float4 sp = make_float4(fb, (float)zi, (float)yi, (float)xi);
            *(float4*)(out + OUT_SP + (row0 + r) * 4) = sp;   // always 16B aligned
            out[OUT_VAL + row0 + r] = 1.0f;
        }
        __syncthreads();

        // feats region: linear coalesced copy
        float* f0 = out + row0 * 5;
        int total5 = (int)(total * 5);
        for (int j = tid; j < total5; j += 256) f0[j] = fbuf[j];
    } else {
        // fallback: direct scattered emit (never taken on bench data)
        const float4* pd = (const float4*)(dop + chunk);
        unsigned wb = k0 + wbase;
#pragma unroll
        for (int t = 0; t < 4; ++t) {
            float4 a = pc[t * 64 + lane];
            float4 d4 = pd[t * 64 + lane];
            float vvv[4] = {a.x, a.y, a.z, a.w};
            float ddd[4] = {d4.x, d4.y, d4.z, d4.w};
            bool m0 = kk[4 * t + 0] >= SELKEY, m1 = kk[4 * t + 1] >= SELKEY,
                 m2 = kk[4 * t + 2] >= SELKEY, m3 = kk[4 * t + 3] >= SELKEY;
            unsigned s_all = (unsigned)__popcll(bb[4 * t + 0] & lt) + (unsigned)__popcll(bb[4 * t + 1] & lt)
                           + (unsigned)__popcll(bb[4 * t + 2] & lt) + (unsigned)__popcll(bb[4 * t + 3] & lt);
            unsigned r = wb + s_all;
            int i0 = i0base + t * 256;
            if (m0) emit_row(out, b, r, i0 + 0, vvv[0], ddd[0]);
            r += (unsigned)m0;
            if (m1) emit_row(out, b, r, i0 + 1, vvv[1], ddd[1]);
            r += (unsigned)m1;
            if (m2) emit_row(out, b, r, i0 + 2, vvv[2], ddd[2]);
            r += (unsigned)m2;
            if (m3) emit_row(out, b, r, i0 + 3, vvv[3], ddd[3]);
            wb += (unsigned)__popcll(bb[4 * t + 0]) + (unsigned)__popcll(bb[4 * t + 1])
                + (unsigned)__popcll(bb[4 * t + 2]) + (unsigned)__popcll(bb[4 * t + 3]);
        }
    }
}

// ---------------- zero-fill invalid tail rows ----------------
__global__ void fill_k(float* __restrict__ out, const unsigned* __restrict__ ws) {
    int g = blockIdx.x * 256 + threadIdx.x;
    if (g >= Bn * Kn) return;
    int b = g / Kn;
    int k = g - b * Kn;
    if ((unsigned)k >= ws[CNT_OFF + b]) {
        size_t row = (size_t)g;
        float* f = out + row * 5;
        f[0] = 0.f; f[1] = 0.f; f[2] = 0.f; f[3] = 0.f; f[4] = 0.f;
        float* s = out + OUT_SP + row * 4;
        s[0] = 0.f; s[1] = 0.f; s[2] = 0.f; s[3] = 0.f;
        out[OUT_VAL + row] = 0.f;
    }
}

extern "C" void kernel_launch(void* const* d_in, const int* in_sizes, int n_in,
                              void* d_out, int out_size, void* d_ws, size_t ws_size,
                              hipStream_t stream) {
    const float* cube = (const float*)d_in[0];
    const float* dop = (const float*)d_in[1];
    float* out = (float*)d_out;
    unsigned* ws = (unsigned*)d_ws;
    unsigned* ou = (unsigned*)d_out;

    hipMemsetAsync(d_ws, 0, ZERO_WORDS * sizeof(unsigned), stream);

    hipLaunchKernelGGL(hist1_k, dim3(Bn * 250), dim3(256), 0, stream, cube, ws);
    hipLaunchKernelGGL(pick1_k, dim3(Bn), dim3(256), 0, stream, ws);
    hipLaunchKernelGGL(collect_k, dim3(Bn * 1000), dim3(256), 0, stream, cube, ou, ws);
    hipLaunchKernelGGL(hist2b_k, dim3(Bn * 64), dim3(256), 0, stream, ou, ws);
    hipLaunchKernelGGL(pick2b_k, dim3(Bn), dim3(256), 0, stream, ws);
    hipLaunchKernelGGL(hist3b_k, dim3(Bn * 64), dim3(256), 0, stream, ou, ws);
    hipLaunchKernelGGL(pick3b_k, dim3(Bn), dim3(256), 0, stream, ws);
    hipLaunchKernelGGL(cand_bc_k, dim3(Bn * 1000), dim3(256), 0, stream, ou, ws);
    hipLaunchKernelGGL(scan_k, dim3(Bn), dim3(256), 0, stream, ws);
    hipLaunchKernelGGL(scatter_k, dim3(Bn * 1000), dim3(256), 0, stream, cube, dop, out, ws);
    hipLaunchKernelGGL(fill_k, dim3((Bn * Kn + 255) / 256), dim3(256), 0, stream, out, ws);
}